// Round 13
// baseline (183.946 us; speedup 1.0000x reference)
//
#include <hip/hip_runtime.h>

typedef unsigned short u16;
typedef unsigned int u32;
typedef _Float16 f16;
typedef __attribute__((ext_vector_type(8))) _Float16 h8v;
typedef __attribute__((ext_vector_type(4))) float f4v;
typedef __attribute__((ext_vector_type(4))) u32 u4v;

#define SC_RZ (-1.44269504f)   // -1/ln2 : r,z gates -> sigm = rcp(1+exp2(acc))
#define SC_N  (2.88539008f)    //  2/ln2 : n gate    -> tanh = 1-2*rcp(1+exp2(acc))

__device__ __forceinline__ u16 f2h_bits(float f){
  f16 h = (f16)f;
  return __builtin_bit_cast(u16, h);
}
__device__ __forceinline__ float h2f(u16 u){
  return (float)__builtin_bit_cast(f16, u);
}
__device__ __forceinline__ float sigmf(float x){
  return __builtin_amdgcn_rcpf(1.f + __expf(-x));
}
__device__ __forceinline__ float fexp2(float x){
#if __has_builtin(__builtin_amdgcn_exp2f)
  return __builtin_amdgcn_exp2f(x);
#else
  return exp2f(x);
#endif
}

// ---------------------------------------------------------------------------
// k_pre: merged prep + m2 + zz (R11-measured config, restored verbatim).
//  bid 0..61    : A16G row n (f16 softmax(relu(E E^T)), [64][72] padded)
//  bid 62       : alpha; zero A16G rows 62,63
//  bid 63..110  : WhhH fp16 [3g][64 j][64 k] PRE-SCALED, k=62 = biases
//  bid 111..606 : M2[((t*62+n)*192+col)*24+k] PRE-SCALED
//  bid 607..1118: zz (4 batches per block)
// ---------------------------------------------------------------------------
__global__ __launch_bounds__(256) void k_pre(
    const float* __restrict__ E, const float* __restrict__ Tp,
    const float* __restrict__ Whh, const float* __restrict__ bih,
    const float* __restrict__ bhh, const float* __restrict__ Wp,
    const float* __restrict__ bp, const float* __restrict__ Wih,
    const float* __restrict__ PI, const float* __restrict__ Wz,
    u16* __restrict__ A16G, float* __restrict__ alpha,
    u16* __restrict__ WhhH, u16* __restrict__ M2, float* __restrict__ zzO)
{
  const int bid = blockIdx.x, tid = threadIdx.x;
  __shared__ float w2s[1240];
  __shared__ float bias[62];
  __shared__ float red[128];

  if (bid < 62){
    const int n = bid;
    if (tid < 64){
      float e0 = E[n*3], e1 = E[n*3+1], e2 = E[n*3+2];
      float s = -1e30f;
      if (tid < 62){
        float d = e0*E[tid*3] + e1*E[tid*3+1] + e2*E[tid*3+2];
        s = d > 0.f ? d : 0.f;
      }
      float mx = s;
      #pragma unroll
      for (int off = 1; off < 64; off <<= 1) mx = fmaxf(mx, __shfl_xor(mx, off));
      float e = (tid < 62) ? __expf(s - mx) : 0.f;
      float sum = e;
      #pragma unroll
      for (int off = 1; off < 64; off <<= 1) sum += __shfl_xor(sum, off);
      if (tid < 62) A16G[n*72 + tid] = f2h_bits(e / sum);
      else A16G[n*72 + tid] = 0;
    } else if (tid < 72){
      A16G[n*72 + tid] = 0;
    }
  } else if (bid == 62){
    if (tid < 8){
      int t = tid;
      float mx = -1e30f;
      for (int s = 0; s <= t; ++s) mx = fmaxf(mx, Tp[t*9+s]);
      float sum = 0.f;
      for (int s = 0; s <= t; ++s) sum += __expf(Tp[t*9+s] - mx);
      float inv = 1.f / sum;
      for (int s = 0; s < 9; ++s)
        alpha[t*9+s] = (s <= t) ? __expf(Tp[t*9+s] - mx) * inv : 0.f;
    }
    if (tid >= 64 && tid < 208) A16G[62*72 + (tid - 64)] = 0;
  } else if (bid < 111){
    int i = (bid - 63)*256 + tid;
    if (i < 12288){
      int row = i >> 6, k = i & 63, g = row >> 6, jj = row & 63;
      float sc = (g == 2) ? SC_N : SC_RZ;
      float vh = 0.f;
      if (jj < 62){
        if (k < 62) vh = Whh[(g*62+jj)*62 + k];
        else if (k == 62) vh = (g < 2) ? (bih[g*62+jj] + bhh[g*62+jj]) : bhh[124+jj];
      }
      WhhH[i] = f2h_bits(vh * sc);
    }
  } else if (bid < 607){
    const int mb = bid - 111;            // t*62+n
    const int t = mb / 62, n = mb % 62;
    const float e0 = E[n*3], e1 = E[n*3+1], e2 = E[n*3+2];
    for (int i = tid; i < 1240; i += 256){
      int o = i / 20, k = i % 20, c = k >> 1, kl = k & 1;
      w2s[i] = e0*Wp[(((t*3+0)*2+kl)*10+c)*62 + o]
             + e1*Wp[(((t*3+1)*2+kl)*10+c)*62 + o]
             + e2*Wp[(((t*3+2)*2+kl)*10+c)*62 + o];
    }
    if (tid < 62)
      bias[tid] = e0*bp[(t*3+0)*62+tid] + e1*bp[(t*3+1)*62+tid]
                + e2*bp[(t*3+2)*62+tid];
    __syncthreads();
    for (int i = tid; i < 2304; i += 256){   // 192 cols x 12 dwords (K=24)
      int col = i / 12, d = i % 12, g = col >> 6, jj = col & 63;
      float sc = (g == 2) ? SC_N : SC_RZ;
      unsigned outw = 0;
      if (jj < 62){
        const float* wr = Wih + (g*62+jj)*62;
        if (d < 10){
          int k0 = 2*d;
          float v0 = 0.f, v1 = 0.f;
          for (int o = 0; o < 62; ++o){
            float w = wr[o];
            v0 += w * w2s[o*20 + k0];
            v1 += w * w2s[o*20 + k0 + 1];
          }
          outw = (unsigned)f2h_bits(v0*sc) | ((unsigned)f2h_bits(v1*sc) << 16);
        } else if (d == 10){
          float v0 = 0.f;
          for (int o = 0; o < 62; ++o) v0 += wr[o]*bias[o];
          float v1 = (g == 2) ? bih[124+jj] : 0.f;
          outw = (unsigned)f2h_bits(v0*sc) | ((unsigned)f2h_bits(v1*sc) << 16);
        }
      }
      ((unsigned*)M2)[((size_t)mb*192 + col)*12 + d] = outw;
    }
  } else {
    const int b0 = (bid - 607)*4;
    float acc[32];
    #pragma unroll
    for (int i = 0; i < 32; ++i) acc[i] = 0.f;
    const float4* p0 = (const float4*)(PI + (size_t)(b0+0)*10000);
    const float4* p1 = (const float4*)(PI + (size_t)(b0+1)*10000);
    const float4* p2 = (const float4*)(PI + (size_t)(b0+2)*10000);
    const float4* p3 = (const float4*)(PI + (size_t)(b0+3)*10000);
    const float4* wz4 = (const float4*)Wz;
    for (int p = tid; p < 2500; p += 256){
      float4 x0 = p0[p], x1 = p1[p], x2 = p2[p], x3 = p3[p];
      #pragma unroll
      for (int t = 0; t < 8; ++t){
        float4 w = wz4[t*2500 + p];
        acc[t*4+0] += x0.x*w.x + x0.y*w.y + x0.z*w.z + x0.w*w.w;
        acc[t*4+1] += x1.x*w.x + x1.y*w.y + x1.z*w.z + x1.w*w.w;
        acc[t*4+2] += x2.x*w.x + x2.y*w.y + x2.z*w.z + x2.w*w.w;
        acc[t*4+3] += x3.x*w.x + x3.y*w.y + x3.z*w.z + x3.w*w.w;
      }
    }
    int lane = tid & 63, wid = tid >> 6;
    #pragma unroll
    for (int i = 0; i < 32; ++i){
      float v = acc[i];
      v += __shfl_xor(v, 1);  v += __shfl_xor(v, 2);  v += __shfl_xor(v, 4);
      v += __shfl_xor(v, 8);  v += __shfl_xor(v, 16); v += __shfl_xor(v, 32);
      if (lane == 0) red[i*4 + wid] = v;
    }
    __syncthreads();
    if (tid < 32){
      float s = red[tid*4] + red[tid*4+1] + red[tid*4+2] + red[tid*4+3];
      int t = tid >> 2, bq = tid & 3;
      zzO[t*2048 + b0 + bq] = sigmf(s);
    }
  }
}

// ---------------------------------------------------------------------------
// k_u v4: LDS diet. Only xT (GEMM B) + xg stay in LDS (22.6 KB -> 7 blk/CU);
// combine reads x straight from global (L1/L2-hot, aligned float2, fp32).
// ---------------------------------------------------------------------------
__global__ __launch_bounds__(256) void k_u(
    const float* __restrict__ x, const u16* __restrict__ A16G,
    const float* __restrict__ alpha, const float* __restrict__ zz,
    u16* __restrict__ U01)
{
  const int b = blockIdx.x, tid = threadIdx.x;
  __shared__ f16 xT[80*72];       // [(s1*10+c)][m]  11520 B
  __shared__ f16 xg[64*84];       // [n][ct] pad 84  10752 B
  __shared__ float al[72];
  __shared__ float zzb[8];

  const float* pxb = x + (size_t)b*5580;
  const float4* px4 = (const float4*)pxb;
  for (int i = tid; i < 1395; i += 256){
    float4 v = px4[i];
    int base = i*4;
    #pragma unroll
    for (int q = 0; q < 4; ++q){
      int idx = base + q;
      int ss = idx / 620, rr = idx % 620, nn = rr / 10, cc = rr % 10;
      if (ss >= 1){
        float fv = (q==0) ? v.x : (q==1) ? v.y : (q==2) ? v.z : v.w;
        xT[((ss-1)*10 + cc)*72 + nn] = (f16)fv;
      }
    }
  }
  for (int i = tid; i < 800; i += 256) xT[(i/10)*72 + 62 + (i%10)] = (f16)0.f;
  if (tid < 72) al[tid] = alpha[tid];
  if (tid < 8) zzb[tid] = zz[tid*2048 + b];
  __syncthreads();

  // ---- MFMA: xg[n][ct] = sum_m A16G[n][m] * xT[ct][m] ----
  {
    const int w_id = tid >> 6, lane = tid & 63, ln = lane & 15, hi = lane >> 4;
    h8v af0 = *(const h8v*)(const void*)(A16G + (w_id*16 + ln)*72 + hi*8);
    h8v af1 = *(const h8v*)(const void*)(A16G + (w_id*16 + ln)*72 + 32 + hi*8);
    f4v Z4 = {0.f, 0.f, 0.f, 0.f};
    #pragma unroll
    for (int Nt = 0; Nt < 5; ++Nt){
      h8v bf0 = *(const h8v*)&xT[(Nt*16 + ln)*72 + hi*8];
      h8v bf1 = *(const h8v*)&xT[(Nt*16 + ln)*72 + 32 + hi*8];
      f4v acc = __builtin_amdgcn_mfma_f32_16x16x32_f16(af0, bf0, Z4, 0,0,0);
      acc = __builtin_amdgcn_mfma_f32_16x16x32_f16(af1, bf1, acc, 0,0,0);
      #pragma unroll
      for (int rg = 0; rg < 4; ++rg)
        xg[(w_id*16 + hi*4 + rg)*84 + Nt*16 + ln] = (f16)acc[rg];
    }
  }
  __syncthreads();

  // ---- combine: one (t,n) row per thread, 2 rounds; x from global (fp32) ----
  #pragma unroll
  for (int r = 0; r < 2; ++r){
    int idx = r*256 + tid;
    if (idx < 496){
      int t = idx / 62, n = idx % 62;
      float alr[9];
      #pragma unroll
      for (int s = 0; s < 9; ++s) alr[s] = al[t*9+s];
      const float z = zzb[t];
      const float* xr = pxb + n*10;           // row stride 620 floats
      float xw[10];
      #pragma unroll
      for (int c = 0; c < 10; ++c) xw[c] = 0.f;
      #pragma unroll
      for (int s = 0; s < 9; ++s){
        const float2* p = (const float2*)(xr + s*620);   // 8B-aligned
        float av = alr[s];
        #pragma unroll
        for (int c2 = 0; c2 < 5; ++c2){
          float2 vv = p[c2];
          xw[2*c2]   = fmaf(av, vv.x, xw[2*c2]);
          xw[2*c2+1] = fmaf(av, vv.y, xw[2*c2+1]);
        }
      }
      const float2* pn = (const float2*)(xr + (t+1)*620);
      const u32* gx = (const u32*)&xg[n*84 + t*10];      // even offset: aligned
      u32 d[12];
      #pragma unroll
      for (int c2 = 0; c2 < 5; ++c2){
        float2 vv = pn[c2];
        u32 gw = gx[c2];
        float u0a = fmaf(z, vv.x, xw[2*c2]);
        float u0b = fmaf(z, vv.y, xw[2*c2+1]);
        float u1a = z * h2f((u16)(gw & 0xffff));
        float u1b = z * h2f((u16)(gw >> 16));
        d[2*c2]   = (u32)f2h_bits(u0a) | ((u32)f2h_bits(u1a) << 16);
        d[2*c2+1] = (u32)f2h_bits(u0b) | ((u32)f2h_bits(u1b) << 16);
      }
      d[10] = (u32)f2h_bits(z) | (0x3C00u << 16);   // [zz | 1.0]
      d[11] = 0;
      u4v* dst = (u4v*)(U01 + ((size_t)(t*62 + n)*2048 + b)*24);
      dst[0] = (u4v){d[0], d[1], d[2], d[3]};
      dst[1] = (u4v){d[4], d[5], d[6], d[7]};
      dst[2] = (u4v){d[8], d[9], d[10], d[11]};
    }
  }
}

// ---------------------------------------------------------------------------
// k_gru: FROZEN 89.6-us config (R11). Prescaled weights + exp2 gates;
// gi = U@M2, gh = H@Whh (biases via homogeneous slots); 1 barrier/step;
// U 1-ahead prefetch; M2 loaded at step start. Block = (n, 32-batch tile).
// ---------------------------------------------------------------------------
__global__ __launch_bounds__(256, 3) void k_gru(
    const u16* __restrict__ U01, const u16* __restrict__ M2,
    const u16* __restrict__ WhhH, float* __restrict__ outSum)
{
  __shared__ f16 Hs[2][32*72];     // stride 72: natural bank rotation
  __shared__ float red[128];

  const int tid = threadIdx.x;
  int bid = blockIdx.x;
  bid = (bid & 7)*496 + (bid >> 3);     // XCD-bijective: same-n -> same XCD
  const int n_idx = bid >> 6;
  const int b0 = (bid & 63) << 5;
  const int lane = tid & 63;
  const int w_id = tid >> 6;
  const int ln = lane & 15;
  const int hi = lane >> 4;
  const int j = w_id*16 + ln;           // this lane's gate column

  // persistent pre-scaled Whh B-fragments (48 VGPR)
  h8v whhF[3][2];
  #pragma unroll
  for (int g = 0; g < 3; ++g)
    #pragma unroll
    for (int ks = 0; ks < 2; ++ks)
      whhF[g][ks] = *(const h8v*)(const void*)(WhhH + (g*64 + j)*64 + ks*32 + hi*8);

  // init both H buffers: zeros, col 62 = 1.0 (homogeneous slot), col 63 = 0
  for (int i = tid; i < 2304; i += 256){
    f16 v = ((i % 72) == 62) ? (f16)1.f : (f16)0.f;
    Hs[0][i] = v; Hs[1][i] = v;
  }

  auto ldU = [&](int t, int mi)->h8v{
    if (hi == 3) return (h8v){};
    return *(const h8v*)(const void*)(U01 +
        ((size_t)(t*62 + n_idx)*2048 + b0 + mi*16 + ln)*24 + hi*8);
  };
  auto ldM = [&](int t, int g)->h8v{
    if (hi == 3) return (h8v){};
    return *(const h8v*)(const void*)(M2 +
        ((size_t)(t*62 + n_idx)*192 + g*64 + j)*24 + hi*8);
  };

  h8v uA0 = ldU(0,0), uA1 = ldU(0,1);
  h8v uB0, uB1;

  float h_reg[8];
  #pragma unroll
  for (int i = 0; i < 8; ++i) h_reg[i] = 0.f;
  __syncthreads();

  #pragma unroll
  for (int t = 0; t < 8; ++t){
    const int p = t & 1;
    h8v mf0 = ldM(t,0), mf1 = ldM(t,1), mf2 = ldM(t,2);
    if (t < 7){ uB0 = ldU(t+1,0); uB1 = ldU(t+1,1); }

    f4v ar[2], az[2], axn[2], ahn[2];
    #pragma unroll
    for (int mi = 0; mi < 2; ++mi){
      ar[mi] = (f4v){0.f,0.f,0.f,0.f};  az[mi] = (f4v){0.f,0.f,0.f,0.f};
      axn[mi] = (f4v){0.f,0.f,0.f,0.f}; ahn[mi] = (f4v){0.f,0.f,0.f,0.f};
    }
    // gh phase: H (incl. bias row 62) x Whh
    #pragma unroll
    for (int ks = 0; ks < 2; ++ks)
      #pragma unroll
      for (int mi = 0; mi < 2; ++mi){
        h8v hf = *(const h8v*)&Hs[p][(mi*16 + ln)*72 + ks*32 + hi*8];
        ar[mi]  = __builtin_amdgcn_mfma_f32_16x16x32_f16(hf, whhF[0][ks], ar[mi], 0,0,0);
        az[mi]  = __builtin_amdgcn_mfma_f32_16x16x32_f16(hf, whhF[1][ks], az[mi], 0,0,0);
        ahn[mi] = __builtin_amdgcn_mfma_f32_16x16x32_f16(hf, whhF[2][ks], ahn[mi], 0,0,0);
      }
    // gi phase: U (incl. zz, 1.0 slots) x M2
    ar[0]  = __builtin_amdgcn_mfma_f32_16x16x32_f16(uA0, mf0, ar[0], 0,0,0);
    ar[1]  = __builtin_amdgcn_mfma_f32_16x16x32_f16(uA1, mf0, ar[1], 0,0,0);
    az[0]  = __builtin_amdgcn_mfma_f32_16x16x32_f16(uA0, mf1, az[0], 0,0,0);
    az[1]  = __builtin_amdgcn_mfma_f32_16x16x32_f16(uA1, mf1, az[1], 0,0,0);
    axn[0] = __builtin_amdgcn_mfma_f32_16x16x32_f16(uA0, mf2, axn[0], 0,0,0);
    axn[1] = __builtin_amdgcn_mfma_f32_16x16x32_f16(uA1, mf2, axn[1], 0,0,0);

    // gates: prescaled -> pure exp2 forms
    const bool last = (t == 7);
    #pragma unroll
    for (int mi = 0; mi < 2; ++mi)
      #pragma unroll
      for (int rg = 0; rg < 4; ++rg){
        float r  = __builtin_amdgcn_rcpf(1.f + fexp2(ar[mi][rg]));
        float zg = __builtin_amdgcn_rcpf(1.f + fexp2(az[mi][rg]));
        float yn = fmaf(r, ahn[mi][rg], axn[mi][rg]);
        float ng = fmaf(-2.f, __builtin_amdgcn_rcpf(1.f + fexp2(yn)), 1.f);
        int idx = mi*4 + rg;
        float hnew = fmaf(zg, h_reg[idx] - ng, ng);
        h_reg[idx] = hnew;
        if (!last && j < 62)
          Hs[p^1][(mi*16 + hi*4 + rg)*72 + j] = (f16)hnew;
      }
    uA0 = uB0; uA1 = uB1;
    __syncthreads();
  }

  // ---- row-sum over hidden dim (mask pad cols 62,63) ----
  #pragma unroll
  for (int mi = 0; mi < 2; ++mi)
    #pragma unroll
    for (int rg = 0; rg < 4; ++rg){
      float v = (j < 62) ? h_reg[mi*4 + rg] : 0.f;
      v += __shfl_xor(v, 1); v += __shfl_xor(v, 2);
      v += __shfl_xor(v, 4); v += __shfl_xor(v, 8);
      if (ln == 0) red[w_id*32 + mi*16 + hi*4 + rg] = v;
    }
  __syncthreads();
  if (tid < 32)
    outSum[(size_t)n_idx*2048 + b0 + tid] =
        red[tid] + red[32+tid] + red[64+tid] + red[96+tid];
}

// ---------------------------------------------------------------------------
// k_mlp: 1 batch per block, 2048 blocks. (frozen from R10)
// ---------------------------------------------------------------------------
__global__ __launch_bounds__(256) void k_mlp(
    const float* __restrict__ outSum,
    const float* __restrict__ W1, const float* __restrict__ b1,
    const float* __restrict__ W2, const float* __restrict__ b2,
    float* __restrict__ out)
{
  const int b = blockIdx.x, tid = threadIdx.x;
  __shared__ float vec[62];
  __shared__ float o1[256];
  if (tid < 62) vec[tid] = outSum[(size_t)tid*2048 + b];
  __syncthreads();
  {
    const float* wr = W1 + tid*62;
    float a = b1[tid];
    #pragma unroll 2
    for (int n = 0; n < 62; ++n) a += wr[n]*vec[n];
    o1[tid] = fmaxf(a, 0.f);
  }
  __syncthreads();
  const int w_id = tid >> 6, lane = tid & 63;
  if (w_id < 3){
    float s = 0.f;
    #pragma unroll
    for (int q = 0; q < 4; ++q){
      int k = q*64 + lane;
      s += o1[k]*W2[w_id*256 + k];
    }
    s += __shfl_xor(s, 1);  s += __shfl_xor(s, 2);  s += __shfl_xor(s, 4);
    s += __shfl_xor(s, 8);  s += __shfl_xor(s, 16); s += __shfl_xor(s, 32);
    if (lane == 0) out[b*3 + w_id] = fmaxf(s + b2[w_id], 0.f);
  }
}

// ---------------------------------------------------------------------------
extern "C" void kernel_launch(void* const* d_in, const int* in_sizes, int n_in,
                              void* d_out, int out_size, void* d_ws, size_t ws_size,
                              hipStream_t stream)
{
  const float* x   = (const float*)d_in[0];
  const float* PI  = (const float*)d_in[1];
  const float* E   = (const float*)d_in[2];
  const float* Wp  = (const float*)d_in[3];
  const float* bp  = (const float*)d_in[4];
  const float* Tp  = (const float*)d_in[5];
  const float* Wz  = (const float*)d_in[6];
  const float* Wih = (const float*)d_in[7];
  const float* Whh = (const float*)d_in[8];
  const float* bih = (const float*)d_in[9];
  const float* bhh = (const float*)d_in[10];
  const float* W1  = (const float*)d_in[11];
  const float* b1  = (const float*)d_in[12];
  const float* W2  = (const float*)d_in[13];
  const float* b2  = (const float*)d_in[14];
  float* out = (float*)d_out;

  char* ws = (char*)d_ws;
  size_t off = 0;
  auto take = [&](size_t bytes)->char*{
    char* p = ws + off; off = (off + bytes + 255) & ~(size_t)255; return p;
  };
  u16*   pA16G  = (u16*)take(4608*2);
  float* palpha = (float*)take(72*4);
  float* pzz    = (float*)take(16384*4);
  u16*   pWhhH  = (u16*)take(12288*2);
  u16*   pM2    = (u16*)take((size_t)496*192*24*2);
  u16*   pU01   = (u16*)take((size_t)496*2048*24*2);
  float* pos    = (float*)take((size_t)126976*4);

  k_pre<<<1119, 256, 0, stream>>>(E, Tp, Whh, bih, bhh, Wp, bp, Wih, PI, Wz,
                                  pA16G, palpha, pWhhH, pM2, pzz);
  k_u<<<2048, 256, 0, stream>>>(x, pA16G, palpha, pzz, pU01);
  k_gru<<<3968, 256, 0, stream>>>(pU01, pM2, pWhhH, pos);
  k_mlp<<<2048, 256, 0, stream>>>(pos, W1, b1, W2, b2, out);
}

// Round 14
// 168.826 us; speedup vs baseline: 1.0896x; 1.0896x over previous
//
#include <hip/hip_runtime.h>

typedef unsigned short u16;
typedef unsigned int u32;
typedef _Float16 f16;
typedef __attribute__((ext_vector_type(8))) _Float16 h8v;
typedef __attribute__((ext_vector_type(4))) float f4v;
typedef __attribute__((ext_vector_type(4))) u32 u4v;

#define SC_RZ (-1.44269504f)   // -1/ln2 : r,z gates -> sigm = rcp(1+exp2(acc))
#define SC_N  (2.88539008f)    //  2/ln2 : n gate    -> tanh = 1-2*rcp(1+exp2(acc))

__device__ __forceinline__ u16 f2h_bits(float f){
  f16 h = (f16)f;
  return __builtin_bit_cast(u16, h);
}
__device__ __forceinline__ float h2f(u16 u){
  return (float)__builtin_bit_cast(f16, u);
}
__device__ __forceinline__ float sigmf(float x){
  return __builtin_amdgcn_rcpf(1.f + __expf(-x));
}
__device__ __forceinline__ float fexp2(float x){
#if __has_builtin(__builtin_amdgcn_exp2f)
  return __builtin_amdgcn_exp2f(x);
#else
  return exp2f(x);
#endif
}

// ---------------------------------------------------------------------------
// k_pre: merged prep + m2 + zz (all independent; concurrent).
//  bid 0..61    : A16G row n (f16 softmax(relu(E E^T)), [64][72] padded)
//  bid 62       : alpha; zero A16G rows 62,63
//  bid 63..110  : WhhH fp16 [3g][64 j][64 k] PRE-SCALED, k=62 = biases
//  bid 111..606 : M2[((t*62+n)*192+col)*24+k] PRE-SCALED: k<20 Wih@w2,
//                 k=20 biasW, k=21 b_ih(n gate), k=22,23 zero
//  bid 607..1118: zz (4 batches per block)
// ---------------------------------------------------------------------------
__global__ __launch_bounds__(256) void k_pre(
    const float* __restrict__ E, const float* __restrict__ Tp,
    const float* __restrict__ Whh, const float* __restrict__ bih,
    const float* __restrict__ bhh, const float* __restrict__ Wp,
    const float* __restrict__ bp, const float* __restrict__ Wih,
    const float* __restrict__ PI, const float* __restrict__ Wz,
    u16* __restrict__ A16G, float* __restrict__ alpha,
    u16* __restrict__ WhhH, u16* __restrict__ M2, float* __restrict__ zzO)
{
  const int bid = blockIdx.x, tid = threadIdx.x;
  __shared__ float w2s[1240];
  __shared__ float bias[62];
  __shared__ float red[128];

  if (bid < 62){
    const int n = bid;
    if (tid < 64){
      float e0 = E[n*3], e1 = E[n*3+1], e2 = E[n*3+2];
      float s = -1e30f;
      if (tid < 62){
        float d = e0*E[tid*3] + e1*E[tid*3+1] + e2*E[tid*3+2];
        s = d > 0.f ? d : 0.f;
      }
      float mx = s;
      #pragma unroll
      for (int off = 1; off < 64; off <<= 1) mx = fmaxf(mx, __shfl_xor(mx, off));
      float e = (tid < 62) ? __expf(s - mx) : 0.f;
      float sum = e;
      #pragma unroll
      for (int off = 1; off < 64; off <<= 1) sum += __shfl_xor(sum, off);
      if (tid < 62) A16G[n*72 + tid] = f2h_bits(e / sum);
      else A16G[n*72 + tid] = 0;
    } else if (tid < 72){
      A16G[n*72 + tid] = 0;
    }
  } else if (bid == 62){
    if (tid < 8){
      int t = tid;
      float mx = -1e30f;
      for (int s = 0; s <= t; ++s) mx = fmaxf(mx, Tp[t*9+s]);
      float sum = 0.f;
      for (int s = 0; s <= t; ++s) sum += __expf(Tp[t*9+s] - mx);
      float inv = 1.f / sum;
      for (int s = 0; s < 9; ++s)
        alpha[t*9+s] = (s <= t) ? __expf(Tp[t*9+s] - mx) * inv : 0.f;
    }
    if (tid >= 64 && tid < 208) A16G[62*72 + (tid - 64)] = 0;
  } else if (bid < 111){
    int i = (bid - 63)*256 + tid;
    if (i < 12288){
      int row = i >> 6, k = i & 63, g = row >> 6, jj = row & 63;
      float sc = (g == 2) ? SC_N : SC_RZ;
      float vh = 0.f;
      if (jj < 62){
        if (k < 62) vh = Whh[(g*62+jj)*62 + k];
        else if (k == 62) vh = (g < 2) ? (bih[g*62+jj] + bhh[g*62+jj]) : bhh[124+jj];
      }
      WhhH[i] = f2h_bits(vh * sc);
    }
  } else if (bid < 607){
    const int mb = bid - 111;            // t*62+n
    const int t = mb / 62, n = mb % 62;
    const float e0 = E[n*3], e1 = E[n*3+1], e2 = E[n*3+2];
    for (int i = tid; i < 1240; i += 256){
      int o = i / 20, k = i % 20, c = k >> 1, kl = k & 1;
      w2s[i] = e0*Wp[(((t*3+0)*2+kl)*10+c)*62 + o]
             + e1*Wp[(((t*3+1)*2+kl)*10+c)*62 + o]
             + e2*Wp[(((t*3+2)*2+kl)*10+c)*62 + o];
    }
    if (tid < 62)
      bias[tid] = e0*bp[(t*3+0)*62+tid] + e1*bp[(t*3+1)*62+tid]
                + e2*bp[(t*3+2)*62+tid];
    __syncthreads();
    for (int i = tid; i < 2304; i += 256){   // 192 cols x 12 dwords (K=24)
      int col = i / 12, d = i % 12, g = col >> 6, jj = col & 63;
      float sc = (g == 2) ? SC_N : SC_RZ;
      unsigned outw = 0;
      if (jj < 62){
        const float* wr = Wih + (g*62+jj)*62;
        if (d < 10){
          int k0 = 2*d;
          float v0 = 0.f, v1 = 0.f;
          for (int o = 0; o < 62; ++o){
            float w = wr[o];
            v0 += w * w2s[o*20 + k0];
            v1 += w * w2s[o*20 + k0 + 1];
          }
          outw = (unsigned)f2h_bits(v0*sc) | ((unsigned)f2h_bits(v1*sc) << 16);
        } else if (d == 10){
          float v0 = 0.f;
          for (int o = 0; o < 62; ++o) v0 += wr[o]*bias[o];
          float v1 = (g == 2) ? bih[124+jj] : 0.f;
          outw = (unsigned)f2h_bits(v0*sc) | ((unsigned)f2h_bits(v1*sc) << 16);
        }
      }
      ((unsigned*)M2)[((size_t)mb*192 + col)*12 + d] = outw;
    }
  } else {
    const int b0 = (bid - 607)*4;
    float acc[32];
    #pragma unroll
    for (int i = 0; i < 32; ++i) acc[i] = 0.f;
    const float4* p0 = (const float4*)(PI + (size_t)(b0+0)*10000);
    const float4* p1 = (const float4*)(PI + (size_t)(b0+1)*10000);
    const float4* p2 = (const float4*)(PI + (size_t)(b0+2)*10000);
    const float4* p3 = (const float4*)(PI + (size_t)(b0+3)*10000);
    const float4* wz4 = (const float4*)Wz;
    for (int p = tid; p < 2500; p += 256){
      float4 x0 = p0[p], x1 = p1[p], x2 = p2[p], x3 = p3[p];
      #pragma unroll
      for (int t = 0; t < 8; ++t){
        float4 w = wz4[t*2500 + p];
        acc[t*4+0] += x0.x*w.x + x0.y*w.y + x0.z*w.z + x0.w*w.w;
        acc[t*4+1] += x1.x*w.x + x1.y*w.y + x1.z*w.z + x1.w*w.w;
        acc[t*4+2] += x2.x*w.x + x2.y*w.y + x2.z*w.z + x2.w*w.w;
        acc[t*4+3] += x3.x*w.x + x3.y*w.y + x3.z*w.z + x3.w*w.w;
      }
    }
    int lane = tid & 63, wid = tid >> 6;
    #pragma unroll
    for (int i = 0; i < 32; ++i){
      float v = acc[i];
      v += __shfl_xor(v, 1);  v += __shfl_xor(v, 2);  v += __shfl_xor(v, 4);
      v += __shfl_xor(v, 8);  v += __shfl_xor(v, 16); v += __shfl_xor(v, 32);
      if (lane == 0) red[i*4 + wid] = v;
    }
    __syncthreads();
    if (tid < 32){
      float s = red[tid*4] + red[tid*4+1] + red[tid*4+2] + red[tid*4+3];
      int t = tid >> 2, bq = tid & 3;
      zzO[t*2048 + b0 + bq] = sigmf(s);
    }
  }
}

// ---------------------------------------------------------------------------
// k_u v3 (R11-measured): vectorized staging (float4 + cvt_pkrtz -> aligned
// u32 LDS writes; xs16 rows padded to 16 for h8v combine reads; xT built in
// the same pass), MFMA A-mix (A frags from global A16G), vectorized combine,
// 3x dwordx4 out.
// ---------------------------------------------------------------------------
__global__ __launch_bounds__(256) void k_u(
    const float* __restrict__ x, const u16* __restrict__ A16G,
    const float* __restrict__ alpha, const float* __restrict__ zz,
    u16* __restrict__ U01)
{
  const int b = blockIdx.x, tid = threadIdx.x;
  __shared__ u16 xs16[558*16];    // [s*62+n][16] (c 0..9 + pad)  17856 B
  __shared__ f16 xT[80*72];       // [(s1*10+c)][m]               11520 B
  __shared__ f16 xg[64*84];       // [n][ct] pad 84               10752 B
  __shared__ float al[72];
  __shared__ float zzb[8];

  const float4* px4 = (const float4*)(x + (size_t)b*5580);
  for (int i = tid; i < 1395; i += 256){
    float4 v = px4[i];
    int base = i*4;
    int s = base / 620, r = base % 620, n = r / 10, c = r % 10;
    u32 p0 = __builtin_bit_cast(u32, __builtin_amdgcn_cvt_pkrtz(v.x, v.y));
    u32 p1 = __builtin_bit_cast(u32, __builtin_amdgcn_cvt_pkrtz(v.z, v.w));
    if (c <= 6){                       // all 4 in one row, aligned u32 pairs
      u32* dst = (u32*)&xs16[(s*62 + n)*16 + c];
      dst[0] = p0; dst[1] = p1;
    } else {                           // c == 8: split across rows
      *(u32*)&xs16[(s*62 + n)*16 + 8] = p0;
      int idx2 = base + 2, s2 = idx2 / 620, r2 = idx2 % 620, n2 = r2 / 10;
      *(u32*)&xs16[(s2*62 + n2)*16 + 0] = p1;
    }
    // xT (transpose) writes for s >= 1 elements
    #pragma unroll
    for (int q = 0; q < 4; ++q){
      int idx = base + q;
      int ss = idx / 620, rr = idx % 620, nn = rr / 10, cc = rr % 10;
      if (ss >= 1){
        u16 hb = (q==0) ? (u16)(p0 & 0xffff) : (q==1) ? (u16)(p0 >> 16)
               : (q==2) ? (u16)(p1 & 0xffff) : (u16)(p1 >> 16);
        xT[((ss-1)*10 + cc)*72 + nn] = __builtin_bit_cast(f16, hb);
      }
    }
  }
  for (int i = tid; i < 800; i += 256) xT[(i/10)*72 + 62 + (i%10)] = (f16)0.f;
  if (tid < 72) al[tid] = alpha[tid];
  if (tid < 8) zzb[tid] = zz[tid*2048 + b];
  __syncthreads();

  // ---- MFMA: xg[n][ct] = sum_m A16G[n][m] * xT[ct][m] ----
  {
    const int w_id = tid >> 6, lane = tid & 63, ln = lane & 15, hi = lane >> 4;
    h8v af0 = *(const h8v*)(const void*)(A16G + (w_id*16 + ln)*72 + hi*8);
    h8v af1 = *(const h8v*)(const void*)(A16G + (w_id*16 + ln)*72 + 32 + hi*8);
    f4v Z4 = {0.f, 0.f, 0.f, 0.f};
    #pragma unroll
    for (int Nt = 0; Nt < 5; ++Nt){
      h8v bf0 = *(const h8v*)&xT[(Nt*16 + ln)*72 + hi*8];
      h8v bf1 = *(const h8v*)&xT[(Nt*16 + ln)*72 + 32 + hi*8];
      f4v acc = __builtin_amdgcn_mfma_f32_16x16x32_f16(af0, bf0, Z4, 0,0,0);
      acc = __builtin_amdgcn_mfma_f32_16x16x32_f16(af1, bf1, acc, 0,0,0);
      #pragma unroll
      for (int rg = 0; rg < 4; ++rg)
        xg[(w_id*16 + hi*4 + rg)*84 + Nt*16 + ln] = (f16)acc[rg];
    }
  }
  __syncthreads();

  // ---- combine: one (t,n) row per thread, 2 rounds; vector LDS reads ----
  #pragma unroll
  for (int r = 0; r < 2; ++r){
    int idx = r*256 + tid;
    if (idx < 496){
      int t = idx / 62, n = idx % 62;
      float alr[9];
      #pragma unroll
      for (int s = 0; s < 9; ++s) alr[s] = al[t*9+s];
      const float z = zzb[t];
      float xw[10];
      #pragma unroll
      for (int c = 0; c < 10; ++c) xw[c] = 0.f;
      #pragma unroll
      for (int s = 0; s < 9; ++s){
        h8v a = *(const h8v*)&xs16[(s*62 + n)*16];        // 32B row, aligned
        u32 bw = *(const u32*)&xs16[(s*62 + n)*16 + 8];
        float av = alr[s];
        #pragma unroll
        for (int c = 0; c < 8; ++c) xw[c] = fmaf(av, (float)a[c], xw[c]);
        xw[8] = fmaf(av, h2f((u16)(bw & 0xffff)), xw[8]);
        xw[9] = fmaf(av, h2f((u16)(bw >> 16)), xw[9]);
      }
      float xn[10];
      {
        h8v a = *(const h8v*)&xs16[((t+1)*62 + n)*16];
        u32 bw = *(const u32*)&xs16[((t+1)*62 + n)*16 + 8];
        #pragma unroll
        for (int c = 0; c < 8; ++c) xn[c] = (float)a[c];
        xn[8] = h2f((u16)(bw & 0xffff));
        xn[9] = h2f((u16)(bw >> 16));
      }
      const u32* gx = (const u32*)&xg[n*84 + t*10];       // even offset: aligned
      u32 d[12];
      #pragma unroll
      for (int c2 = 0; c2 < 5; ++c2){
        u32 gw = gx[c2];
        float u0a = fmaf(z, xn[2*c2],   xw[2*c2]);
        float u0b = fmaf(z, xn[2*c2+1], xw[2*c2+1]);
        float u1a = z * h2f((u16)(gw & 0xffff));
        float u1b = z * h2f((u16)(gw >> 16));
        d[2*c2]   = (u32)f2h_bits(u0a) | ((u32)f2h_bits(u1a) << 16);
        d[2*c2+1] = (u32)f2h_bits(u0b) | ((u32)f2h_bits(u1b) << 16);
      }
      d[10] = (u32)f2h_bits(z) | (0x3C00u << 16);   // [zz | 1.0]
      d[11] = 0;
      u4v* dst = (u4v*)(U01 + ((size_t)(t*62 + n)*2048 + b)*24);
      dst[0] = (u4v){d[0], d[1], d[2], d[3]};
      dst[1] = (u4v){d[4], d[5], d[6], d[7]};
      dst[2] = (u4v){d[8], d[9], d[10], d[11]};
    }
  }
}

// ---------------------------------------------------------------------------
// k_gru: FROZEN 89.6-us config (R11). Prescaled weights + exp2 gates;
// gi = U@M2, gh = H@Whh (biases via homogeneous slots); 1 barrier/step;
// U 1-ahead prefetch; M2 loaded at step start. Block = (n, 32-batch tile).
// ---------------------------------------------------------------------------
__global__ __launch_bounds__(256, 3) void k_gru(
    const u16* __restrict__ U01, const u16* __restrict__ M2,
    const u16* __restrict__ WhhH, float* __restrict__ outSum)
{
  __shared__ f16 Hs[2][32*72];     // stride 72: natural bank rotation
  __shared__ float red[128];

  const int tid = threadIdx.x;
  int bid = blockIdx.x;
  bid = (bid & 7)*496 + (bid >> 3);     // XCD-bijective: same-n -> same XCD
  const int n_idx = bid >> 6;
  const int b0 = (bid & 63) << 5;
  const int lane = tid & 63;
  const int w_id = tid >> 6;
  const int ln = lane & 15;
  const int hi = lane >> 4;
  const int j = w_id*16 + ln;           // this lane's gate column

  // persistent pre-scaled Whh B-fragments (48 VGPR)
  h8v whhF[3][2];
  #pragma unroll
  for (int g = 0; g < 3; ++g)
    #pragma unroll
    for (int ks = 0; ks < 2; ++ks)
      whhF[g][ks] = *(const h8v*)(const void*)(WhhH + (g*64 + j)*64 + ks*32 + hi*8);

  // init both H buffers: zeros, col 62 = 1.0 (homogeneous slot), col 63 = 0
  for (int i = tid; i < 2304; i += 256){
    f16 v = ((i % 72) == 62) ? (f16)1.f : (f16)0.f;
    Hs[0][i] = v; Hs[1][i] = v;
  }

  auto ldU = [&](int t, int mi)->h8v{
    if (hi == 3) return (h8v){};
    return *(const h8v*)(const void*)(U01 +
        ((size_t)(t*62 + n_idx)*2048 + b0 + mi*16 + ln)*24 + hi*8);
  };
  auto ldM = [&](int t, int g)->h8v{
    if (hi == 3) return (h8v){};
    return *(const h8v*)(const void*)(M2 +
        ((size_t)(t*62 + n_idx)*192 + g*64 + j)*24 + hi*8);
  };

  h8v uA0 = ldU(0,0), uA1 = ldU(0,1);
  h8v uB0, uB1;

  float h_reg[8];
  #pragma unroll
  for (int i = 0; i < 8; ++i) h_reg[i] = 0.f;
  __syncthreads();

  #pragma unroll
  for (int t = 0; t < 8; ++t){
    const int p = t & 1;
    h8v mf0 = ldM(t,0), mf1 = ldM(t,1), mf2 = ldM(t,2);
    if (t < 7){ uB0 = ldU(t+1,0); uB1 = ldU(t+1,1); }

    f4v ar[2], az[2], axn[2], ahn[2];
    #pragma unroll
    for (int mi = 0; mi < 2; ++mi){
      ar[mi] = (f4v){0.f,0.f,0.f,0.f};  az[mi] = (f4v){0.f,0.f,0.f,0.f};
      axn[mi] = (f4v){0.f,0.f,0.f,0.f}; ahn[mi] = (f4v){0.f,0.f,0.f,0.f};
    }
    // gh phase: H (incl. bias row 62) x Whh
    #pragma unroll
    for (int ks = 0; ks < 2; ++ks)
      #pragma unroll
      for (int mi = 0; mi < 2; ++mi){
        h8v hf = *(const h8v*)&Hs[p][(mi*16 + ln)*72 + ks*32 + hi*8];
        ar[mi]  = __builtin_amdgcn_mfma_f32_16x16x32_f16(hf, whhF[0][ks], ar[mi], 0,0,0);
        az[mi]  = __builtin_amdgcn_mfma_f32_16x16x32_f16(hf, whhF[1][ks], az[mi], 0,0,0);
        ahn[mi] = __builtin_amdgcn_mfma_f32_16x16x32_f16(hf, whhF[2][ks], ahn[mi], 0,0,0);
      }
    // gi phase: U (incl. zz, 1.0 slots) x M2
    ar[0]  = __builtin_amdgcn_mfma_f32_16x16x32_f16(uA0, mf0, ar[0], 0,0,0);
    ar[1]  = __builtin_amdgcn_mfma_f32_16x16x32_f16(uA1, mf0, ar[1], 0,0,0);
    az[0]  = __builtin_amdgcn_mfma_f32_16x16x32_f16(uA0, mf1, az[0], 0,0,0);
    az[1]  = __builtin_amdgcn_mfma_f32_16x16x32_f16(uA1, mf1, az[1], 0,0,0);
    axn[0] = __builtin_amdgcn_mfma_f32_16x16x32_f16(uA0, mf2, axn[0], 0,0,0);
    axn[1] = __builtin_amdgcn_mfma_f32_16x16x32_f16(uA1, mf2, axn[1], 0,0,0);

    // gates: prescaled -> pure exp2 forms
    const bool last = (t == 7);
    #pragma unroll
    for (int mi = 0; mi < 2; ++mi)
      #pragma unroll
      for (int rg = 0; rg < 4; ++rg){
        float r  = __builtin_amdgcn_rcpf(1.f + fexp2(ar[mi][rg]));
        float zg = __builtin_amdgcn_rcpf(1.f + fexp2(az[mi][rg]));
        float yn = fmaf(r, ahn[mi][rg], axn[mi][rg]);
        float ng = fmaf(-2.f, __builtin_amdgcn_rcpf(1.f + fexp2(yn)), 1.f);
        int idx = mi*4 + rg;
        float hnew = fmaf(zg, h_reg[idx] - ng, ng);
        h_reg[idx] = hnew;
        if (!last && j < 62)
          Hs[p^1][(mi*16 + hi*4 + rg)*72 + j] = (f16)hnew;
      }
    uA0 = uB0; uA1 = uB1;
    __syncthreads();
  }

  // ---- row-sum over hidden dim (mask pad cols 62,63) ----
  #pragma unroll
  for (int mi = 0; mi < 2; ++mi)
    #pragma unroll
    for (int rg = 0; rg < 4; ++rg){
      float v = (j < 62) ? h_reg[mi*4 + rg] : 0.f;
      v += __shfl_xor(v, 1); v += __shfl_xor(v, 2);
      v += __shfl_xor(v, 4); v += __shfl_xor(v, 8);
      if (ln == 0) red[w_id*32 + mi*16 + hi*4 + rg] = v;
    }
  __syncthreads();
  if (tid < 32)
    outSum[(size_t)n_idx*2048 + b0 + tid] =
        red[tid] + red[32+tid] + red[64+tid] + red[96+tid];
}

// ---------------------------------------------------------------------------
// k_mlp: 1 batch per block, 2048 blocks. W1 row per thread from L2;
// W2 phase via 3 wave reductions.
// ---------------------------------------------------------------------------
__global__ __launch_bounds__(256) void k_mlp(
    const float* __restrict__ outSum,
    const float* __restrict__ W1, const float* __restrict__ b1,
    const float* __restrict__ W2, const float* __restrict__ b2,
    float* __restrict__ out)
{
  const int b = blockIdx.x, tid = threadIdx.x;
  __shared__ float vec[62];
  __shared__ float o1[256];
  if (tid < 62) vec[tid] = outSum[(size_t)tid*2048 + b];
  __syncthreads();
  {
    const float* wr = W1 + tid*62;
    float a = b1[tid];
    #pragma unroll 2
    for (int n = 0; n < 62; ++n) a += wr[n]*vec[n];
    o1[tid] = fmaxf(a, 0.f);
  }
  __syncthreads();
  const int w_id = tid >> 6, lane = tid & 63;
  if (w_id < 3){
    float s = 0.f;
    #pragma unroll
    for (int q = 0; q < 4; ++q){
      int k = q*64 + lane;
      s += o1[k]*W2[w_id*256 + k];
    }
    s += __shfl_xor(s, 1);  s += __shfl_xor(s, 2);  s += __shfl_xor(s, 4);
    s += __shfl_xor(s, 8);  s += __shfl_xor(s, 16); s += __shfl_xor(s, 32);
    if (lane == 0) out[b*3 + w_id] = fmaxf(s + b2[w_id], 0.f);
  }
}

// ---------------------------------------------------------------------------
extern "C" void kernel_launch(void* const* d_in, const int* in_sizes, int n_in,
                              void* d_out, int out_size, void* d_ws, size_t ws_size,
                              hipStream_t stream)
{
  const float* x   = (const float*)d_in[0];
  const float* PI  = (const float*)d_in[1];
  const float* E   = (const float*)d_in[2];
  const float* Wp  = (const float*)d_in[3];
  const float* bp  = (const float*)d_in[4];
  const float* Tp  = (const float*)d_in[5];
  const float* Wz  = (const float*)d_in[6];
  const float* Wih = (const float*)d_in[7];
  const float* Whh = (const float*)d_in[8];
  const float* bih = (const float*)d_in[9];
  const float* bhh = (const float*)d_in[10];
  const float* W1  = (const float*)d_in[11];
  const float* b1  = (const float*)d_in[12];
  const float* W2  = (const float*)d_in[13];
  const float* b2  = (const float*)d_in[14];
  float* out = (float*)d_out;

  char* ws = (char*)d_ws;
  size_t off = 0;
  auto take = [&](size_t bytes)->char*{
    char* p = ws + off; off = (off + bytes + 255) & ~(size_t)255; return p;
  };
  u16*   pA16G  = (u16*)take(4608*2);
  float* palpha = (float*)take(72*4);
  float* pzz    = (float*)take(16384*4);
  u16*   pWhhH  = (u16*)take(12288*2);
  u16*   pM2    = (u16*)take((size_t)496*192*24*2);
  u16*   pU01   = (u16*)take((size_t)496*2048*24*2);
  float* pos    = (float*)take((size_t)126976*4);

  k_pre<<<1119, 256, 0, stream>>>(E, Tp, Whh, bih, bhh, Wp, bp, Wih, PI, Wz,
                                  pA16G, palpha, pWhhH, pM2, pzz);
  k_u<<<2048, 256, 0, stream>>>(x, pA16G, palpha, pzz, pU01);
  k_gru<<<3968, 256, 0, stream>>>(pU01, pM2, pWhhH, pos);
  k_mlp<<<2048, 256, 0, stream>>>(pos, W1, b1, W2, b2, out);
}